// Round 1
// baseline (470.339 us; speedup 1.0000x reference)
//
#include <hip/hip_runtime.h>
#include <hip/hip_bf16.h>

// sparselinear: out[b*S + s] = sum_{e: row[e]==s} x[b*G + col[e]] * W[e] + bias[s]
// B=64 (== wavefront), G=20000, S=200000, NNZ=2e6.
//
// Pipeline (all on `stream`, graph-capture safe):
//   1. memset cnt=0
//   2. transpose x [B,G] -> xT [G,B]  (lane=batch coalescing for gathers)
//   3. histogram rows -> cnt
//   4. exclusive scan cnt -> off (3 kernels), cursor=off
//   5. scatter edges into row-sorted (scol, sw) via cursor atomics
//   6. compute: one wave per row, lane=batch; shfl-broadcast staged edges

#define WAVE 64

__global__ void transpose64_kernel(const float* __restrict__ x,
                                   float* __restrict__ xT, int G) {
    __shared__ float tile[64][65];   // +1 pad: conflict-free both phases
    const int t  = threadIdx.x;
    const int g0 = blockIdx.x * 64;
    {
        const int j  = t & 63;   // g offset within tile (coalesced load dim)
        const int b0 = t >> 6;   // 0..3
        if (g0 + j < G) {
            #pragma unroll
            for (int it = 0; it < 16; ++it) {
                const int b = b0 + it * 4;
                tile[j][b] = x[(size_t)b * G + g0 + j];
            }
        }
    }
    __syncthreads();
    {
        const int b  = t & 63;   // batch (coalesced store dim)
        const int j0 = t >> 6;
        #pragma unroll
        for (int it = 0; it < 16; ++it) {
            const int j = j0 + it * 4;
            if (g0 + j < G) xT[(size_t)(g0 + j) * WAVE + b] = tile[j][b];
        }
    }
}

__global__ void hist_kernel(const int* __restrict__ row, int* __restrict__ cnt,
                            int nnz) {
    const int i = blockIdx.x * 256 + threadIdx.x;
    if (i < nnz) atomicAdd(&cnt[row[i]], 1);
}

// Per-block exclusive scan over chunks of 2048 (256 thr x 8). Writes local
// exclusive scan to off[], block total to sums[blockIdx].
__global__ void scan_local_kernel(const int* __restrict__ cnt,
                                  int* __restrict__ off,
                                  int* __restrict__ sums, int S) {
    __shared__ int sd[256];
    const int t = threadIdx.x;
    const int base = blockIdx.x * 2048 + t * 8;
    int v[8];
    int tsum = 0;
    #pragma unroll
    for (int k = 0; k < 8; ++k) {
        const int idx = base + k;
        const int c = (idx < S) ? cnt[idx] : 0;
        v[k] = tsum;           // exclusive within thread
        tsum += c;
    }
    sd[t] = tsum;
    __syncthreads();
    for (int o = 1; o < 256; o <<= 1) {
        const int a = (t >= o) ? sd[t - o] : 0;
        __syncthreads();
        sd[t] += a;
        __syncthreads();
    }
    const int tex = sd[t] - tsum;   // exclusive across threads
    if (t == 255) sums[blockIdx.x] = sd[255];
    #pragma unroll
    for (int k = 0; k < 8; ++k) {
        const int idx = base + k;
        if (idx < S) off[idx] = tex + v[k];
    }
}

__global__ void scan_sums_kernel(int* __restrict__ sums, int n) {
    __shared__ int sd[256];
    const int t = threadIdx.x;
    const int v = (t < n) ? sums[t] : 0;
    sd[t] = v;
    __syncthreads();
    for (int o = 1; o < 256; o <<= 1) {
        const int a = (t >= o) ? sd[t - o] : 0;
        __syncthreads();
        sd[t] += a;
        __syncthreads();
    }
    if (t < n) sums[t] = sd[t] - v;   // exclusive
}

__global__ void scan_add_kernel(int* __restrict__ off,
                                const int* __restrict__ sums,
                                int* __restrict__ cur, int S) {
    const int i = blockIdx.x * 256 + threadIdx.x;
    if (i < S) {
        const int v = off[i] + sums[i >> 11];
        off[i] = v;
        cur[i] = v;
    }
}

__global__ void scatter_kernel(const int* __restrict__ row,
                               const int* __restrict__ col,
                               const float* __restrict__ w,
                               int* __restrict__ cur, int* __restrict__ scol,
                               float* __restrict__ sw, int nnz) {
    const int i = blockIdx.x * 256 + threadIdx.x;
    if (i < nnz) {
        const int r = row[i];
        const int p = atomicAdd(&cur[r], 1);
        scol[p] = col[i];
        sw[p]   = w[i];
    }
}

// One wave per row. lane = batch. Stage <=64 edges into lane registers,
// shfl-broadcast each edge; xT gather is a coalesced 256B wave read.
__global__ void compute_kernel(const float* __restrict__ xT,
                               const int* __restrict__ scol,
                               const float* __restrict__ sw,
                               const int* __restrict__ off,
                               const int* __restrict__ cnt,
                               const float* __restrict__ bias,
                               float* __restrict__ out, int S) {
    const int lane = threadIdx.x & 63;
    const int row  = blockIdx.x * 4 + (threadIdx.x >> 6);
    if (row >= S) return;
    const int start = off[row];
    const int n     = cnt[row];
    float acc = 0.f;
    for (int bse = 0; bse < n; bse += WAVE) {
        int m = n - bse;
        if (m > WAVE) m = WAVE;
        int   c  = 0;
        float wv = 0.f;
        if (lane < m) {
            c  = scol[start + bse + lane];
            wv = sw[start + bse + lane];
        }
        for (int i = 0; i < m; ++i) {
            const int   ci = __shfl(c, i, WAVE);
            const float wi = __shfl(wv, i, WAVE);
            acc += xT[(size_t)ci * WAVE + lane] * wi;
        }
    }
    out[(size_t)lane * S + row] = acc + bias[row];
}

extern "C" void kernel_launch(void* const* d_in, const int* in_sizes, int n_in,
                              void* d_out, int out_size, void* d_ws, size_t ws_size,
                              hipStream_t stream) {
    const float* x    = (const float*)d_in[0];
    const float* W    = (const float*)d_in[1];
    const float* bias = (const float*)d_in[2];
    const int*   idx  = (const int*)d_in[3];

    const int NNZ = in_sizes[1];
    const int S   = in_sizes[2];
    const int B   = out_size / S;        // 64
    const int G   = in_sizes[0] / B;     // 20000
    const int* rowi = idx;
    const int* coli = idx + NNZ;
    float* out = (float*)d_out;

    // workspace layout (256B-aligned slabs)
    char* ws = (char*)d_ws;
    size_t o = 0;
    auto alloc = [&](size_t bytes) {
        void* p = ws + o;
        o = (o + bytes + 255) & ~(size_t)255;
        return p;
    };
    float* xT   = (float*)alloc((size_t)G * B * sizeof(float));
    int*   cnt  = (int*)  alloc((size_t)S * sizeof(int));
    int*   off  = (int*)  alloc((size_t)S * sizeof(int));
    int*   cur  = (int*)  alloc((size_t)S * sizeof(int));
    int*   sums = (int*)  alloc(1024 * sizeof(int));
    int*   scol = (int*)  alloc((size_t)NNZ * sizeof(int));
    float* sw   = (float*)alloc((size_t)NNZ * sizeof(float));
    (void)ws_size; (void)n_in;

    hipMemsetAsync(cnt, 0, (size_t)S * sizeof(int), stream);

    const int tgrid = (G + 63) / 64;
    transpose64_kernel<<<tgrid, 256, 0, stream>>>(x, xT, G);

    const int egrid = (NNZ + 255) / 256;
    hist_kernel<<<egrid, 256, 0, stream>>>(rowi, cnt, NNZ);

    const int nchunks = (S + 2047) / 2048;   // 98 (<=256 required)
    scan_local_kernel<<<nchunks, 256, 0, stream>>>(cnt, off, sums, S);
    scan_sums_kernel<<<1, 256, 0, stream>>>(sums, nchunks);
    scan_add_kernel<<<(S + 255) / 256, 256, 0, stream>>>(off, sums, cur, S);

    scatter_kernel<<<egrid, 256, 0, stream>>>(rowi, coli, W, cur, scol, sw, NNZ);

    compute_kernel<<<(S + 3) / 4, 256, 0, stream>>>(xT, scol, sw, off, cnt,
                                                    bias, out, S);
}

// Round 2
// 394.540 us; speedup vs baseline: 1.1921x; 1.1921x over previous
//
#include <hip/hip_runtime.h>
#include <hip/hip_bf16.h>

// sparselinear: out[b*S + s] = sum_{e: row[e]==s} x[b*G + col[e]] * W[e] + bias[s]
// B=64 (== wavefront), G=20000, S=200000, NNZ=2e6.
//
// Pipeline (all on `stream`, graph-capture safe):
//   1. memset cnt=0
//   2. transpose x [B,G] -> xT [G,B]  (lane=batch coalescing for gathers)
//   3. histogram rows -> cnt
//   4. exclusive scan cnt -> off (3 kernels), cursor=off
//   5. scatter edges into row-sorted packed (col,w) uint2 records
//   6. compute: block = 64 rows x 64 batches; readlane edge broadcast,
//      4x-unrolled gathers, LDS-transposed coalesced output tile.

#define WAVE 64

__global__ void transpose64_kernel(const float* __restrict__ x,
                                   float* __restrict__ xT, int G) {
    __shared__ float tile[64][65];   // +1 pad: conflict-free both phases
    const int t  = threadIdx.x;
    const int g0 = blockIdx.x * 64;
    {
        const int j  = t & 63;   // g offset within tile (coalesced load dim)
        const int b0 = t >> 6;   // 0..3
        if (g0 + j < G) {
            #pragma unroll
            for (int it = 0; it < 16; ++it) {
                const int b = b0 + it * 4;
                tile[j][b] = x[(size_t)b * G + g0 + j];
            }
        }
    }
    __syncthreads();
    {
        const int b  = t & 63;   // batch (coalesced store dim)
        const int j0 = t >> 6;
        #pragma unroll
        for (int it = 0; it < 16; ++it) {
            const int j = j0 + it * 4;
            if (g0 + j < G) xT[(size_t)(g0 + j) * WAVE + b] = tile[j][b];
        }
    }
}

__global__ void hist_kernel(const int* __restrict__ row, int* __restrict__ cnt,
                            int nnz) {
    const int i = blockIdx.x * 256 + threadIdx.x;
    if (i < nnz) atomicAdd(&cnt[row[i]], 1);
}

// Per-block exclusive scan over chunks of 2048 (256 thr x 8). Writes local
// exclusive scan to off[], block total to sums[blockIdx].
__global__ void scan_local_kernel(const int* __restrict__ cnt,
                                  int* __restrict__ off,
                                  int* __restrict__ sums, int S) {
    __shared__ int sd[256];
    const int t = threadIdx.x;
    const int base = blockIdx.x * 2048 + t * 8;
    int v[8];
    int tsum = 0;
    #pragma unroll
    for (int k = 0; k < 8; ++k) {
        const int idx = base + k;
        const int c = (idx < S) ? cnt[idx] : 0;
        v[k] = tsum;           // exclusive within thread
        tsum += c;
    }
    sd[t] = tsum;
    __syncthreads();
    for (int o = 1; o < 256; o <<= 1) {
        const int a = (t >= o) ? sd[t - o] : 0;
        __syncthreads();
        sd[t] += a;
        __syncthreads();
    }
    const int tex = sd[t] - tsum;   // exclusive across threads
    if (t == 255) sums[blockIdx.x] = sd[255];
    #pragma unroll
    for (int k = 0; k < 8; ++k) {
        const int idx = base + k;
        if (idx < S) off[idx] = tex + v[k];
    }
}

__global__ void scan_sums_kernel(int* __restrict__ sums, int n) {
    __shared__ int sd[256];
    const int t = threadIdx.x;
    const int v = (t < n) ? sums[t] : 0;
    sd[t] = v;
    __syncthreads();
    for (int o = 1; o < 256; o <<= 1) {
        const int a = (t >= o) ? sd[t - o] : 0;
        __syncthreads();
        sd[t] += a;
        __syncthreads();
    }
    if (t < n) sums[t] = sd[t] - v;   // exclusive
}

__global__ void scan_add_kernel(int* __restrict__ off,
                                const int* __restrict__ sums,
                                int* __restrict__ cur, int S) {
    const int i = blockIdx.x * 256 + threadIdx.x;
    if (i < S) {
        const int v = off[i] + sums[i >> 11];
        off[i] = v;
        cur[i] = v;
    }
}

// Pack (col, w) into one 8B record: single scattered store instead of two.
__global__ void scatter_kernel(const int* __restrict__ row,
                               const int* __restrict__ col,
                               const float* __restrict__ w,
                               int* __restrict__ cur, uint2* __restrict__ sedge,
                               int nnz) {
    const int i = blockIdx.x * 256 + threadIdx.x;
    if (i < nnz) {
        const int r = row[i];
        const int p = atomicAdd(&cur[r], 1);
        sedge[p] = make_uint2((unsigned)col[i], __float_as_uint(w[i]));
    }
}

// Block = 4 waves = 64 rows x 64 batches. lane = batch.
// Per row: stage <=64 packed edges coalesced into lane regs, broadcast with
// v_readlane (scalar pipe, uniform index), 4x-unrolled independent gathers.
// Results go through an LDS 64x64 tile so the output store is 256B coalesced
// per wave (kills the 2.7x write amplification of per-lane strided stores).
__global__ __launch_bounds__(256) void compute_kernel(
        const float* __restrict__ xT,
        const uint2* __restrict__ sedge,
        const int* __restrict__ off,
        const int* __restrict__ cnt,
        const float* __restrict__ bias,
        float* __restrict__ out, int S) {
    __shared__ float tile[64][65];
    const int lane = threadIdx.x & 63;
    const int wv   = threadIdx.x >> 6;
    const int r0   = blockIdx.x * 64;

    #pragma unroll 1
    for (int k = 0; k < 16; ++k) {
        const int rl  = wv * 16 + k;
        const int row = r0 + rl;
        float acc = 0.f;
        float bs  = 0.f;
        if (row < S) {
            // make row metadata wave-uniform (SGPR) for scalar loops/readlane
            const int start = __builtin_amdgcn_readfirstlane(off[row]);
            const int n     = __builtin_amdgcn_readfirstlane(cnt[row]);
            bs = bias[row];
            for (int base = 0; base < n; base += WAVE) {
                int m = n - base;
                if (m > WAVE) m = WAVE;
                uint2 e = make_uint2(0u, 0u);
                if (lane < m) e = sedge[start + base + lane];
                const int cx = (int)e.x;
                const int wx = (int)e.y;
                int i = 0;
                for (; i + 4 <= m; i += 4) {
                    const int c0 = __builtin_amdgcn_readlane(cx, i);
                    const int c1 = __builtin_amdgcn_readlane(cx, i + 1);
                    const int c2 = __builtin_amdgcn_readlane(cx, i + 2);
                    const int c3 = __builtin_amdgcn_readlane(cx, i + 3);
                    const float w0 = __int_as_float(__builtin_amdgcn_readlane(wx, i));
                    const float w1 = __int_as_float(__builtin_amdgcn_readlane(wx, i + 1));
                    const float w2 = __int_as_float(__builtin_amdgcn_readlane(wx, i + 2));
                    const float w3 = __int_as_float(__builtin_amdgcn_readlane(wx, i + 3));
                    const float v0 = xT[c0 * WAVE + lane];
                    const float v1 = xT[c1 * WAVE + lane];
                    const float v2 = xT[c2 * WAVE + lane];
                    const float v3 = xT[c3 * WAVE + lane];
                    acc += v0 * w0;
                    acc += v1 * w1;
                    acc += v2 * w2;
                    acc += v3 * w3;
                }
                for (; i < m; ++i) {
                    const int   c0 = __builtin_amdgcn_readlane(cx, i);
                    const float w0 = __int_as_float(__builtin_amdgcn_readlane(wx, i));
                    acc += xT[c0 * WAVE + lane] * w0;
                }
            }
        }
        tile[rl][lane] = acc + bs;
    }
    __syncthreads();
    // write phase: wave wv covers batches [wv*16, wv*16+16), lane = row offset
    #pragma unroll
    for (int k = 0; k < 16; ++k) {
        const int b = wv * 16 + k;
        if (r0 + lane < S)
            out[(size_t)b * S + r0 + lane] = tile[lane][b];
    }
}

extern "C" void kernel_launch(void* const* d_in, const int* in_sizes, int n_in,
                              void* d_out, int out_size, void* d_ws, size_t ws_size,
                              hipStream_t stream) {
    const float* x    = (const float*)d_in[0];
    const float* W    = (const float*)d_in[1];
    const float* bias = (const float*)d_in[2];
    const int*   idx  = (const int*)d_in[3];

    const int NNZ = in_sizes[1];
    const int S   = in_sizes[2];
    const int B   = out_size / S;        // 64
    const int G   = in_sizes[0] / B;     // 20000
    const int* rowi = idx;
    const int* coli = idx + NNZ;
    float* out = (float*)d_out;

    // workspace layout (256B-aligned slabs)
    char* ws = (char*)d_ws;
    size_t o = 0;
    auto alloc = [&](size_t bytes) {
        void* p = ws + o;
        o = (o + bytes + 255) & ~(size_t)255;
        return p;
    };
    float* xT    = (float*)alloc((size_t)G * B * sizeof(float));
    int*   cnt   = (int*)  alloc((size_t)S * sizeof(int));
    int*   off   = (int*)  alloc((size_t)S * sizeof(int));
    int*   cur   = (int*)  alloc((size_t)S * sizeof(int));
    int*   sums  = (int*)  alloc(1024 * sizeof(int));
    uint2* sedge = (uint2*)alloc((size_t)NNZ * sizeof(uint2));
    (void)ws_size; (void)n_in;

    hipMemsetAsync(cnt, 0, (size_t)S * sizeof(int), stream);

    const int tgrid = (G + 63) / 64;
    transpose64_kernel<<<tgrid, 256, 0, stream>>>(x, xT, G);

    const int egrid = (NNZ + 255) / 256;
    hist_kernel<<<egrid, 256, 0, stream>>>(rowi, cnt, NNZ);

    const int nchunks = (S + 2047) / 2048;   // 98 (<=256 required)
    scan_local_kernel<<<nchunks, 256, 0, stream>>>(cnt, off, sums, S);
    scan_sums_kernel<<<1, 256, 0, stream>>>(sums, nchunks);
    scan_add_kernel<<<(S + 255) / 256, 256, 0, stream>>>(off, sums, cur, S);

    scatter_kernel<<<egrid, 256, 0, stream>>>(rowi, coli, W, cur, sedge, NNZ);

    compute_kernel<<<(S + 63) / 64, 256, 0, stream>>>(xT, sedge, off, cnt,
                                                      bias, out, S);
}